// Round 1
// baseline (154.294 us; speedup 1.0000x reference)
//
#include <hip/hip_runtime.h>
#include <hip/hip_bf16.h>

typedef unsigned short u16;
typedef __bf16 bf16x8 __attribute__((ext_vector_type(8)));
typedef float f32x4 __attribute__((ext_vector_type(4)));

__device__ __forceinline__ u16 f2bf(float f) {
    unsigned u = __builtin_bit_cast(unsigned, f);
    unsigned r = (u + 0x7fffu + ((u >> 16) & 1u)) >> 16;
    return (u16)r;
}

// ---------------- f32 -> bf16 elementwise convert (vectorized) ----------------
__global__ __launch_bounds__(256) void conv_f32_bf16(const float* __restrict__ src,
                                                     u16* __restrict__ dst, int n4) {
    int i = blockIdx.x * 256 + threadIdx.x;
    if (i < n4) {
        float4 v = ((const float4*)src)[i];
        ushort4 o;
        o.x = f2bf(v.x); o.y = f2bf(v.y); o.z = f2bf(v.z); o.w = f2bf(v.w);
        ((ushort4*)dst)[i] = o;
    }
}

// ------------- f32 (R x C) -> bf16 transposed (C x R) via LDS tile -------------
__global__ __launch_bounds__(256) void transpose_f32_bf16(const float* __restrict__ src,
                                                          u16* __restrict__ dst,
                                                          int R, int C) {
    __shared__ float tile[32][33];
    int r0 = blockIdx.y * 32, c0 = blockIdx.x * 32;
    int tx = threadIdx.x;   // 0..31
    int ty = threadIdx.y;   // 0..7
    for (int i = ty; i < 32; i += 8)
        tile[i][tx] = src[(size_t)(r0 + i) * C + (c0 + tx)];
    __syncthreads();
    for (int j = ty; j < 32; j += 8)
        dst[(size_t)(c0 + j) * R + (r0 + tx)] = f2bf(tile[tx][j]);
}

// ---------------- bf16 GEMM: C(MxN) = A(MxK) * Bt(NxK)^T ----------------
// m97 structure: 128x128 tile, BK=32, 4 waves (2x2), 4x4 16x16x32 frags/wave,
// global_load_lds width 16, two barriers per K-step.
#define GLDS16(g, l)                                                      \
    __builtin_amdgcn_global_load_lds(                                     \
        (const __attribute__((address_space(1))) void*)(g),               \
        (__attribute__((address_space(3))) void*)(l), 16, 0, 0)

template <int OUT_BF16>
__global__ __launch_bounds__(256) void gemm_bt(const u16* __restrict__ A,
                                               const u16* __restrict__ Bt,
                                               void* __restrict__ Cv,
                                               int M, int N, int K) {
    __shared__ u16 sA[128 * 32];
    __shared__ u16 sB[128 * 32];

    const int t = threadIdx.x;
    const int lane = t & 63;
    const int w = t >> 6;
    const int wr = w >> 1, wc = w & 1;
    const int l15 = lane & 15, l4 = lane >> 4;
    const int row0 = blockIdx.y * 128, col0 = blockIdx.x * 128;

    f32x4 acc[4][4] = {};

    // staging: 512 16B segments per operand; seg s -> row s>>2, k-chunk (s&3)*8
    const int sr = t >> 2;
    const int sk = (t & 3) * 8;

    const int nK = K >> 5;
    for (int kt = 0; kt < nK; ++kt) {
        const int k0 = kt << 5;
        GLDS16(A + (size_t)(row0 + sr) * K + k0 + sk,        sA + t * 8);
        GLDS16(A + (size_t)(row0 + sr + 64) * K + k0 + sk,   sA + (t + 256) * 8);
        GLDS16(Bt + (size_t)(col0 + sr) * K + k0 + sk,       sB + t * 8);
        GLDS16(Bt + (size_t)(col0 + sr + 64) * K + k0 + sk,  sB + (t + 256) * 8);
        __syncthreads();

        bf16x8 af[4], bfr[4];
#pragma unroll
        for (int m = 0; m < 4; ++m)
            af[m] = *(const bf16x8*)&sA[(wr * 64 + m * 16 + l15) * 32 + l4 * 8];
#pragma unroll
        for (int n = 0; n < 4; ++n)
            bfr[n] = *(const bf16x8*)&sB[(wc * 64 + n * 16 + l15) * 32 + l4 * 8];
#pragma unroll
        for (int m = 0; m < 4; ++m)
#pragma unroll
            for (int n = 0; n < 4; ++n)
                acc[m][n] = __builtin_amdgcn_mfma_f32_16x16x32_bf16(af[m], bfr[n], acc[m][n], 0, 0, 0);
        __syncthreads();
    }

    // epilogue: D row = (lane>>4)*4 + j, col = lane&15  [verified layout]
#pragma unroll
    for (int m = 0; m < 4; ++m) {
#pragma unroll
        for (int n = 0; n < 4; ++n) {
            int r = row0 + wr * 64 + m * 16 + l4 * 4;
            int c = col0 + wc * 64 + n * 16 + l15;
#pragma unroll
            for (int j = 0; j < 4; ++j) {
                float v = acc[m][n][j];
                if (OUT_BF16)
                    ((u16*)Cv)[(size_t)(r + j) * N + c] = f2bf(v);
                else
                    ((float*)Cv)[(size_t)(r + j) * N + c] = v;
            }
        }
    }
}

// dims: x(4096,1024)  V0(1024,2048) V1(2048,2048) V2(2048,1024)
// d_in order (setup_inputs dict order): x, V0, W0, V1, W1, V2, W2
extern "C" void kernel_launch(void* const* d_in, const int* in_sizes, int n_in,
                              void* d_out, int out_size, void* d_ws, size_t ws_size,
                              hipStream_t stream) {
    const float* x  = (const float*)d_in[0];
    const float* V0 = (const float*)d_in[1];
    const float* V1 = (const float*)d_in[3];
    const float* V2 = (const float*)d_in[5];

    char* ws = (char*)d_ws;
    u16* xb  = (u16*)(ws);                          // 8 MB  (4096x1024 bf16)
    u16* V0t = (u16*)(ws + ((size_t)8 << 20));      // 4 MB  (2048x1024)
    u16* V1t = (u16*)(ws + ((size_t)12 << 20));     // 8 MB  (2048x2048)
    u16* V2t = (u16*)(ws + ((size_t)20 << 20));     // 4 MB  (1024x2048)
    u16* T1  = (u16*)(ws + ((size_t)24 << 20));     // 16 MB (4096x2048)
    u16* T2  = (u16*)(ws + ((size_t)40 << 20));     // 16 MB (4096x2048)

    // convert x to bf16
    conv_f32_bf16<<<4096, 256, 0, stream>>>(x, xb, 4096 * 1024 / 4);
    // transpose+convert weights to bf16 N x K
    transpose_f32_bf16<<<dim3(2048 / 32, 1024 / 32), dim3(32, 8), 0, stream>>>(V0, V0t, 1024, 2048);
    transpose_f32_bf16<<<dim3(2048 / 32, 2048 / 32), dim3(32, 8), 0, stream>>>(V1, V1t, 2048, 2048);
    transpose_f32_bf16<<<dim3(1024 / 32, 2048 / 32), dim3(32, 8), 0, stream>>>(V2, V2t, 2048, 1024);

    // chain: T1 = x@V0, T2 = T1@V1, out = T2@V2
    gemm_bt<1><<<dim3(2048 / 128, 4096 / 128), 256, 0, stream>>>(xb, V0t, T1, 4096, 2048, 1024);
    gemm_bt<1><<<dim3(2048 / 128, 4096 / 128), 256, 0, stream>>>(T1, V1t, T2, 4096, 2048, 2048);
    gemm_bt<0><<<dim3(1024 / 128, 4096 / 128), 256, 0, stream>>>(T2, V2t, d_out, 4096, 1024, 2048);
}

// Round 2
// 88.418 us; speedup vs baseline: 1.7451x; 1.7451x over previous
//
#include <hip/hip_runtime.h>
#include <hip/hip_bf16.h>

typedef unsigned short u16;
typedef __bf16 bf16x8 __attribute__((ext_vector_type(8)));
typedef float f32x4 __attribute__((ext_vector_type(4)));

__device__ __forceinline__ u16 f2bf(float f) {
    unsigned u = __builtin_bit_cast(unsigned, f);
    unsigned r = (u + 0x7fffu + ((u >> 16) & 1u)) >> 16;
    return (u16)r;
}

// ---------------- f32 -> bf16 elementwise convert (vectorized) ----------------
__global__ __launch_bounds__(256) void conv_f32_bf16(const float* __restrict__ src,
                                                     u16* __restrict__ dst, int n4) {
    int i = blockIdx.x * 256 + threadIdx.x;
    if (i < n4) {
        float4 v = ((const float4*)src)[i];
        ushort4 o;
        o.x = f2bf(v.x); o.y = f2bf(v.y); o.z = f2bf(v.z); o.w = f2bf(v.w);
        ((ushort4*)dst)[i] = o;
    }
}

// ------------- f32 (R x C) -> bf16 transposed (C x R) via LDS tile -------------
__global__ __launch_bounds__(256) void transpose_f32_bf16(const float* __restrict__ src,
                                                          u16* __restrict__ dst,
                                                          int R, int C) {
    __shared__ float tile[32][33];
    int r0 = blockIdx.y * 32, c0 = blockIdx.x * 32;
    int tx = threadIdx.x;   // 0..31
    int ty = threadIdx.y;   // 0..7
    for (int i = ty; i < 32; i += 8)
        tile[i][tx] = src[(size_t)(r0 + i) * C + (c0 + tx)];
    __syncthreads();
    for (int j = ty; j < 32; j += 8)
        dst[(size_t)(c0 + j) * R + (r0 + tx)] = f2bf(tile[tx][j]);
}

// ---------------- bf16 GEMM: Cpart(z) = A(M x Kc slice) * Bt(N x Kc slice)^T --
// 128x128 tile, BK=32, 8 waves (2 row-groups x 4 col-groups), per-wave 64x32,
// global_load_lds width 16, bf16 partial output at z*M*N.
#define GLDS16(g, l)                                                      \
    __builtin_amdgcn_global_load_lds(                                     \
        (const __attribute__((address_space(1))) void*)(g),               \
        (__attribute__((address_space(3))) void*)(l), 16, 0, 0)

__global__ __launch_bounds__(512) void gemm_bt(const u16* __restrict__ A,
                                               const u16* __restrict__ Bt,
                                               u16* __restrict__ Cpart,
                                               int M, int N, int Ktot, int Kc) {
    __shared__ u16 sA[128 * 32];
    __shared__ u16 sB[128 * 32];

    const int t = threadIdx.x;
    const int lane = t & 63;
    const int w = t >> 6;             // 0..7
    const int wr = w >> 2, wc = w & 3;
    const int l15 = lane & 15, l4 = lane >> 4;
    const int row0 = blockIdx.y * 128, col0 = blockIdx.x * 128;
    const int kbase = blockIdx.z * Kc;

    f32x4 acc[4][2] = {};

    // staging: 512 16B segments per operand; thread t -> row t>>2, k-chunk (t&3)*8
    const int sr = t >> 2;
    const int sk = (t & 3) * 8;

    const int nK = Kc >> 5;
    for (int kt = 0; kt < nK; ++kt) {
        const int k0 = kbase + (kt << 5);
        GLDS16(A  + (size_t)(row0 + sr) * Ktot + k0 + sk, sA + t * 8);
        GLDS16(Bt + (size_t)(col0 + sr) * Ktot + k0 + sk, sB + t * 8);
        __syncthreads();

        bf16x8 af[4], bfr[2];
#pragma unroll
        for (int m = 0; m < 4; ++m)
            af[m] = *(const bf16x8*)&sA[(wr * 64 + m * 16 + l15) * 32 + l4 * 8];
#pragma unroll
        for (int n = 0; n < 2; ++n)
            bfr[n] = *(const bf16x8*)&sB[(wc * 32 + n * 16 + l15) * 32 + l4 * 8];
#pragma unroll
        for (int m = 0; m < 4; ++m)
#pragma unroll
            for (int n = 0; n < 2; ++n)
                acc[m][n] = __builtin_amdgcn_mfma_f32_16x16x32_bf16(af[m], bfr[n], acc[m][n], 0, 0, 0);
        __syncthreads();
    }

    // epilogue: D row = (lane>>4)*4 + j, col = lane&15  [verified layout]
    const size_t zoff = (size_t)blockIdx.z * M * N;
#pragma unroll
    for (int m = 0; m < 4; ++m) {
#pragma unroll
        for (int n = 0; n < 2; ++n) {
            int r = row0 + wr * 64 + m * 16 + l4 * 4;
            int c = col0 + wc * 32 + n * 16 + l15;
#pragma unroll
            for (int j = 0; j < 4; ++j)
                Cpart[zoff + (size_t)(r + j) * N + c] = f2bf(acc[m][n][j]);
        }
    }
}

// -------- sum KS bf16 partial buffers -> bf16 or f32 output (8 elems/thread) --
template <int KS, int F32OUT>
__global__ __launch_bounds__(256) void reduce_parts(const u16* __restrict__ part,
                                                    void* __restrict__ out, int mn) {
    int i = blockIdx.x * 256 + threadIdx.x;
    int n8 = mn >> 3;
    if (i >= n8) return;
    float s[8] = {0, 0, 0, 0, 0, 0, 0, 0};
#pragma unroll
    for (int z = 0; z < KS; ++z) {
        uint4 v = ((const uint4*)(part + (size_t)z * mn))[i];
        unsigned a0 = v.x, a1 = v.y, a2 = v.z, a3 = v.w;
        s[0] += __builtin_bit_cast(float, a0 << 16);
        s[1] += __builtin_bit_cast(float, a0 & 0xffff0000u);
        s[2] += __builtin_bit_cast(float, a1 << 16);
        s[3] += __builtin_bit_cast(float, a1 & 0xffff0000u);
        s[4] += __builtin_bit_cast(float, a2 << 16);
        s[5] += __builtin_bit_cast(float, a2 & 0xffff0000u);
        s[6] += __builtin_bit_cast(float, a3 << 16);
        s[7] += __builtin_bit_cast(float, a3 & 0xffff0000u);
    }
    if (F32OUT) {
        float4 o0 = {s[0], s[1], s[2], s[3]};
        float4 o1 = {s[4], s[5], s[6], s[7]};
        ((float4*)out)[2 * i] = o0;
        ((float4*)out)[2 * i + 1] = o1;
    } else {
        uint4 o;
        o.x = (unsigned)f2bf(s[0]) | ((unsigned)f2bf(s[1]) << 16);
        o.y = (unsigned)f2bf(s[2]) | ((unsigned)f2bf(s[3]) << 16);
        o.z = (unsigned)f2bf(s[4]) | ((unsigned)f2bf(s[5]) << 16);
        o.w = (unsigned)f2bf(s[6]) | ((unsigned)f2bf(s[7]) << 16);
        ((uint4*)out)[i] = o;
    }
}

// dims: x(4096,1024)  V0(1024,2048) V1(2048,2048) V2(2048,1024)
// out = x @ ((V0@V1)@V2):
//   P1  = V0@V1                    (1024x2048 bf16)
//   P2t = V2^T @ P1^T              (1024x1024 bf16)  == (P1@V2)^T, N x K layout for G
//   G   = x @ P2                   (4096x1024 f32 -> d_out)
// d_in order: x, V0, W0, V1, W1, V2, W2
extern "C" void kernel_launch(void* const* d_in, const int* in_sizes, int n_in,
                              void* d_out, int out_size, void* d_ws, size_t ws_size,
                              hipStream_t stream) {
    const float* x  = (const float*)d_in[0];
    const float* V0 = (const float*)d_in[1];
    const float* V1 = (const float*)d_in[3];
    const float* V2 = (const float*)d_in[5];

    char* ws = (char*)d_ws;
    u16* xb   = (u16*)(ws);                          // 8 MB  (4096x1024)
    u16* V0b  = (u16*)(ws + ((size_t)8 << 20));      // 4 MB  (1024x2048, row-major)
    u16* V1t  = (u16*)(ws + ((size_t)12 << 20));     // 8 MB  (2048x2048, = V1^T)
    u16* V2t  = (u16*)(ws + ((size_t)20 << 20));     // 4 MB  (1024x2048, = V2^T)
    u16* P1   = (u16*)(ws + ((size_t)24 << 20));     // 4 MB  (1024x2048)
    u16* P2t  = (u16*)(ws + ((size_t)28 << 20));     // 2 MB  (1024x1024)
    u16* part = (u16*)(ws + ((size_t)30 << 20));     // 16 MB max (split-K partials)

    // input conversions
    conv_f32_bf16<<<4096, 256, 0, stream>>>(x, xb, 4096 * 1024 / 4);
    conv_f32_bf16<<<2048, 256, 0, stream>>>(V0, V0b, 1024 * 2048 / 4);
    transpose_f32_bf16<<<dim3(64, 64), dim3(32, 8), 0, stream>>>(V1, V1t, 2048, 2048);
    transpose_f32_bf16<<<dim3(32, 64), dim3(32, 8), 0, stream>>>(V2, V2t, 2048, 1024);

    // P1 = V0 @ V1 : M=1024, N=2048, K=2048, split-K 4x512
    gemm_bt<<<dim3(16, 8, 4), 512, 0, stream>>>(V0b, V1t, part, 1024, 2048, 2048, 512);
    reduce_parts<4, 0><<<1024, 256, 0, stream>>>(part, P1, 1024 * 2048);

    // P2t = V2^T @ P1^T : M=1024, N=1024, K=2048, split-K 8x256
    gemm_bt<<<dim3(8, 8, 8), 512, 0, stream>>>(V2t, P1, part, 1024, 1024, 2048, 256);
    reduce_parts<8, 0><<<512, 256, 0, stream>>>(part, P2t, 1024 * 1024);

    // G = x @ P2 : M=4096, N=1024, K=1024, split-K 2x512
    gemm_bt<<<dim3(8, 32, 2), 512, 0, stream>>>(xb, P2t, part, 4096, 1024, 1024, 512);
    reduce_parts<2, 1><<<2048, 256, 0, stream>>>(part, d_out, 4096 * 1024);
}